// Round 7
// baseline (190.600 us; speedup 1.0000x reference)
//
#include <hip/hip_runtime.h>
#include <hip/hip_bf16.h>

// Problem shape (fixed by the reference setup_inputs)
constexpr int B = 16, F = 16, H = 256, W = 256;
constexpr int HW = H * W;               // 65536
constexpr int SPATIAL = B * HW;         // 1,048,576 spatial locations
constexpr int NBLOCKS = 2048;
constexpr int NTHREADS = 512;           // 8 waves/block
constexpr int NVALS = 65;               // s[16], c[16], dtot[16], sall[16], call
constexpr int PLANE4 = HW / 4;          // 16384 float4 (or mask-dwords) per (b,f) plane
constexpr int BSTRIDE4 = F * PLANE4;    // 262144 per batch index
constexpr int FQ = 4;                   // features per quarter-wave

typedef float f32x4 __attribute__((ext_vector_type(4)));

// R7: R5 (source batching) and R6 (sched_barrier) both failed to raise
// per-wave loads-in-flight above ~2 (VGPR stayed 24: the interleaving happens
// before the machine scheduler). This version forces it with volatile inline
// asm: 4 mask dwords + 8 dwordx4 issued back-to-back, consumption gated by
// explicit s_waitcnt vmcnt(8)/vmcnt(0) whose tied "+v" operands pin the uses
// below the wait. launch_bounds(512,4) = 128-reg cap -> no spill possible at
// the ~70-reg peak (R3 lesson: a too-tight cap spilled 47 MB of scratch).
__global__ __launch_bounds__(NTHREADS, 4) void heatloss_main(
        const float* __restrict__ inp, const float* __restrict__ tgt,
        const unsigned int* __restrict__ msk, float* __restrict__ partials) {
    const int tid  = threadIdx.x;
    const int wave = tid >> 6;               // 0..7
    const int lane = tid & 63;
    const int l16  = lane & 15;
    const int q    = lane >> 4;              // quarter: features q*4 .. q*4+3
    const int g    = (blockIdx.x * 8 + wave) * 16 + l16;   // float4-group id
    const int b    = g >> 14;                // g / PLANE4
    const int hw4  = g & (PLANE4 - 1);
    const int base = b * BSTRIDE4 + hw4 + q * (FQ * PLANE4);  // float4-group index

    // Byte offsets for the saddr-form global loads.
    const unsigned int moff0 = (unsigned int)(base) * 4u;               // mask dword
    const unsigned int moff1 = moff0 + PLANE4 * 4u;
    const unsigned int moff2 = moff0 + 2u * PLANE4 * 4u;
    const unsigned int moff3 = moff0 + 3u * PLANE4 * 4u;
    const unsigned int doff0 = (unsigned int)(base) * 16u;              // float4
    const unsigned int doff1 = doff0 + PLANE4 * 16u;
    const unsigned int doff2 = doff0 + 2u * PLANE4 * 16u;
    const unsigned int doff3 = doff0 + 3u * PLANE4 * 16u;

    // ---- issue all 12 loads back-to-back (masks first) ----
    unsigned int m0, m1, m2, m3;
    f32x4 a0, a1, a2, a3, t0, t1, t2, t3;
    asm volatile("global_load_dword %0, %1, %2"   : "=v"(m0) : "v"(moff0), "s"(msk));
    asm volatile("global_load_dword %0, %1, %2"   : "=v"(m1) : "v"(moff1), "s"(msk));
    asm volatile("global_load_dword %0, %1, %2"   : "=v"(m2) : "v"(moff2), "s"(msk));
    asm volatile("global_load_dword %0, %1, %2"   : "=v"(m3) : "v"(moff3), "s"(msk));
    asm volatile("global_load_dwordx4 %0, %1, %2" : "=v"(a0) : "v"(doff0), "s"(inp));
    asm volatile("global_load_dwordx4 %0, %1, %2" : "=v"(a1) : "v"(doff1), "s"(inp));
    asm volatile("global_load_dwordx4 %0, %1, %2" : "=v"(a2) : "v"(doff2), "s"(inp));
    asm volatile("global_load_dwordx4 %0, %1, %2" : "=v"(a3) : "v"(doff3), "s"(inp));
    asm volatile("global_load_dwordx4 %0, %1, %2" : "=v"(t0) : "v"(doff0), "s"(tgt));
    asm volatile("global_load_dwordx4 %0, %1, %2" : "=v"(t1) : "v"(doff1), "s"(tgt));
    asm volatile("global_load_dwordx4 %0, %1, %2" : "=v"(t2) : "v"(doff2), "s"(tgt));
    asm volatile("global_load_dwordx4 %0, %1, %2" : "=v"(t3) : "v"(doff3), "s"(tgt));

    // ---- wait for the 4 mask loads only (8 data loads stay in flight) ----
    asm volatile("s_waitcnt vmcnt(8)" : "+v"(m0), "+v"(m1), "+v"(m2), "+v"(m3));

    unsigned int anyu = m0 | m1 | m2 | m3;
    anyu |= __shfl_xor(anyu, 16, 64);        // combine quarters...
    anyu |= __shfl_xor(anyu, 32, 64);        // ...-> any over all 16 features
    const float af0 = (anyu & 0x000000FFu) ? 1.f : 0.f;
    const float af1 = (anyu & 0x0000FF00u) ? 1.f : 0.f;
    const float af2 = (anyu & 0x00FF0000u) ? 1.f : 0.f;
    const float af3 = (anyu & 0xFF000000u) ? 1.f : 0.f;
    const float call = (q == 0) ? (af0 + af1) + (af2 + af3) : 0.f;  // count once

    // ---- wait for the data, then compute ----
    asm volatile("s_waitcnt vmcnt(0)"
                 : "+v"(a0), "+v"(a1), "+v"(a2), "+v"(a3),
                   "+v"(t0), "+v"(t1), "+v"(t2), "+v"(t3));

    f32x4 av[FQ] = {a0, a1, a2, a3};
    f32x4 tv[FQ] = {t0, t1, t2, t3};
    unsigned int m[FQ] = {m0, m1, m2, m3};
    float s[FQ], c[FQ], dtot[FQ], sall[FQ];
    #pragma unroll
    for (int j = 0; j < FQ; j++) {
        const f32x4 a = av[j];
        const f32x4 t = tv[j];
        const float d0 = fabsf(a.x - t.x);
        const float d1 = fabsf(a.y - t.y);
        const float d2 = fabsf(a.z - t.z);
        const float d3 = fabsf(a.w - t.w);
        const unsigned int mm = m[j];
        const float m0f = (float)( mm        & 0xFFu);
        const float m1f = (float)((mm >> 8)  & 0xFFu);
        const float m2f = (float)((mm >> 16) & 0xFFu);
        const float m3f = (float)( mm >> 24);
        dtot[j] = (d0 + d1) + (d2 + d3);
        s[j]    = m0f * d0 + m1f * d1 + m2f * d2 + m3f * d3;
        c[j]    = (m0f + m1f) + (m2f + m3f);
        sall[j] = af0 * d0 + af1 * d1 + af2 * d2 + af3 * d3;
    }

    // Width-16 reduction (quarters hold disjoint features), LDS across waves.
    __shared__ float red[NTHREADS / 64][NVALS];
    const int fbase = q * FQ;
    #pragma unroll
    for (int j = 0; j < FQ; j++) {
        float xs = s[j], xc = c[j], xd = dtot[j], xa = sall[j];
        #pragma unroll
        for (int o = 8; o > 0; o >>= 1) {
            xs += __shfl_down(xs, o, 16);
            xc += __shfl_down(xc, o, 16);
            xd += __shfl_down(xd, o, 16);
            xa += __shfl_down(xa, o, 16);
        }
        if (l16 == 0) {
            red[wave][ 0 + fbase + j] = xs;
            red[wave][16 + fbase + j] = xc;
            red[wave][32 + fbase + j] = xd;
            red[wave][48 + fbase + j] = xa;
        }
    }
    float xcall = call;
    #pragma unroll
    for (int o = 8; o > 0; o >>= 1) xcall += __shfl_down(xcall, o, 16);
    if (lane == 0) red[wave][64] = xcall;
    __syncthreads();
    if (tid < NVALS) {
        float t = 0.f;
        #pragma unroll
        for (int w2 = 0; w2 < NTHREADS / 64; w2++) t += red[w2][tid];
        partials[tid * NBLOCKS + blockIdx.x] = t;   // layout [65][NBLOCKS]
    }
}

// 8 waves; each wave sums one value's 2048 partials with coalesced loads.
__global__ __launch_bounds__(512) void heatloss_finalize(
        const float* __restrict__ partials, float* __restrict__ out) {
    __shared__ float vals[NVALS];
    const int wave = threadIdx.x >> 6;   // 0..7
    const int lane = threadIdx.x & 63;
    for (int v = wave; v < NVALS; v += 8) {
        const float* p = partials + v * NBLOCKS;
        float x = 0.f;
        #pragma unroll
        for (int i = 0; i < NBLOCKS / 64; i++) x += p[i * 64 + lane];
        #pragma unroll
        for (int o = 32; o > 0; o >>= 1) x += __shfl_down(x, o, 64);
        if (lane == 0) vals[v] = x;
    }
    __syncthreads();
    if (threadIdx.x == 0) {
        const float Nf = (float)SPATIAL;  // per-feature element count (B*H*W)
        const float call = vals[64];
        float lf = 0.f, lbg = 0.f, lall = 0.f;
        #pragma unroll
        for (int f = 0; f < F; f++) {
            const float sf = vals[f], cf = vals[16 + f];
            const float dt = vals[32 + f], sa = vals[48 + f];
            lf += (cf > 0.f) ? sf / cf : 0.f;
            const float sbg = dt - sf, cbg = Nf - cf;
            lbg += (cbg > 0.f) ? sbg / cbg : 0.f;
            lall += (call > 0.f) ? sa / call : 0.f;
        }
        out[0] = (lf / 16.f + lbg / 16.f + lall / 16.f) / 3.f;
    }
}

extern "C" void kernel_launch(void* const* d_in, const int* in_sizes, int n_in,
                              void* d_out, int out_size, void* d_ws, size_t ws_size,
                              hipStream_t stream) {
    const float*        inp = (const float*)d_in[0];
    const float*        tgt = (const float*)d_in[1];
    const unsigned int* msk = (const unsigned int*)d_in[2];   // jnp.bool_ -> 1 byte each
    float* out      = (float*)d_out;
    float* partials = (float*)d_ws;   // NVALS * NBLOCKS floats = 532 KB

    heatloss_main<<<NBLOCKS, NTHREADS, 0, stream>>>(inp, tgt, msk, partials);
    heatloss_finalize<<<1, 512, 0, stream>>>(partials, out);
}

// Round 8
// 185.291 us; speedup vs baseline: 1.0287x; 1.0287x over previous
//
#include <hip/hip_runtime.h>
#include <hip/hip_bf16.h>

// Problem shape (fixed by the reference setup_inputs)
constexpr int B = 16, F = 16, H = 256, W = 256;
constexpr int HW = H * W;               // 65536
constexpr int SPATIAL = B * HW;         // 1,048,576 spatial locations
constexpr int NBLOCKS = 2048;
constexpr int NTHREADS = 512;           // 8 waves/block
constexpr int NVALS = 65;               // s[16], c[16], dtot[16], sall[16], call
constexpr int PLANE4 = HW / 4;          // 16384 float4 (or mask-dwords) per (b,f) plane
constexpr int BSTRIDE4 = F * PLANE4;    // 262144 per batch index
constexpr int FQ = 4;                   // features per quarter-wave

// R8 DISCOVERY: bench dur (190us) minus main (58us) = ~130us constant across
// ALL rounds = the single-block finalize serially pulling 532KB on one CU.
// Fix: 3-stage pipeline. Stage2 = 65 parallel blocks (one per value), stage3 =
// tiny combine. Main kernel reverted to clean R5 form (asm variant measured
// identical; R5/R6/R7 all ~58us — main is NOT the dominant cost right now).
__global__ __launch_bounds__(NTHREADS, 6) void heatloss_main(
        const float4* __restrict__ inp, const float4* __restrict__ tgt,
        const unsigned int* __restrict__ msk, float* __restrict__ partials) {
    const int tid  = threadIdx.x;
    const int wave = tid >> 6;               // 0..7
    const int lane = tid & 63;
    const int l16  = lane & 15;
    const int q    = lane >> 4;              // quarter: features q*4 .. q*4+3
    const int g    = (blockIdx.x * 8 + wave) * 16 + l16;   // float4-group id
    const int b    = g >> 14;                // g / PLANE4
    const int hw4  = g & (PLANE4 - 1);
    const int base = b * BSTRIDE4 + hw4 + q * (FQ * PLANE4);

    unsigned int m[FQ];
    #pragma unroll
    for (int j = 0; j < FQ; j++) m[j] = msk[base + j * PLANE4];
    float4 av[FQ], tv[FQ];
    #pragma unroll
    for (int j = 0; j < FQ; j++) av[j] = inp[base + j * PLANE4];
    #pragma unroll
    for (int j = 0; j < FQ; j++) tv[j] = tgt[base + j * PLANE4];

    unsigned int anyu = m[0] | m[1] | m[2] | m[3];
    anyu |= __shfl_xor(anyu, 16, 64);        // combine quarters...
    anyu |= __shfl_xor(anyu, 32, 64);        // ...-> any over all 16 features
    const float af0 = (anyu & 0x000000FFu) ? 1.f : 0.f;
    const float af1 = (anyu & 0x0000FF00u) ? 1.f : 0.f;
    const float af2 = (anyu & 0x00FF0000u) ? 1.f : 0.f;
    const float af3 = (anyu & 0xFF000000u) ? 1.f : 0.f;
    const float call = (q == 0) ? (af0 + af1) + (af2 + af3) : 0.f;  // count once

    float s[FQ], c[FQ], dtot[FQ], sall[FQ];
    #pragma unroll
    for (int j = 0; j < FQ; j++) {
        const float4 a = av[j];
        const float4 t = tv[j];
        const float d0 = fabsf(a.x - t.x);
        const float d1 = fabsf(a.y - t.y);
        const float d2 = fabsf(a.z - t.z);
        const float d3 = fabsf(a.w - t.w);
        const unsigned int mm = m[j];
        const float m0 = (float)( mm        & 0xFFu);
        const float m1 = (float)((mm >> 8)  & 0xFFu);
        const float m2 = (float)((mm >> 16) & 0xFFu);
        const float m3 = (float)( mm >> 24);
        dtot[j] = (d0 + d1) + (d2 + d3);
        s[j]    = m0 * d0 + m1 * d1 + m2 * d2 + m3 * d3;
        c[j]    = (m0 + m1) + (m2 + m3);
        sall[j] = af0 * d0 + af1 * d1 + af2 * d2 + af3 * d3;
    }

    // Width-16 reduction (quarters hold disjoint features), LDS across waves.
    __shared__ float red[NTHREADS / 64][NVALS];
    const int fbase = q * FQ;
    #pragma unroll
    for (int j = 0; j < FQ; j++) {
        float xs = s[j], xc = c[j], xd = dtot[j], xa = sall[j];
        #pragma unroll
        for (int o = 8; o > 0; o >>= 1) {
            xs += __shfl_down(xs, o, 16);
            xc += __shfl_down(xc, o, 16);
            xd += __shfl_down(xd, o, 16);
            xa += __shfl_down(xa, o, 16);
        }
        if (l16 == 0) {
            red[wave][ 0 + fbase + j] = xs;
            red[wave][16 + fbase + j] = xc;
            red[wave][32 + fbase + j] = xd;
            red[wave][48 + fbase + j] = xa;
        }
    }
    float xcall = call;
    #pragma unroll
    for (int o = 8; o > 0; o >>= 1) xcall += __shfl_down(xcall, o, 16);
    if (lane == 0) red[wave][64] = xcall;
    __syncthreads();
    if (tid < NVALS) {
        float t = 0.f;
        #pragma unroll
        for (int w2 = 0; w2 < NTHREADS / 64; w2++) t += red[w2][tid];
        partials[tid * NBLOCKS + blockIdx.x] = t;   // layout [65][NBLOCKS]
    }
}

// Stage 2: 65 blocks, one per value; block v coalesced-sums its 2048 partials.
__global__ __launch_bounds__(256) void heatloss_reduce(
        const float* __restrict__ partials, float* __restrict__ vals) {
    const int v = blockIdx.x;                // 0..64
    const int t = threadIdx.x;               // 0..255
    const float* p = partials + v * NBLOCKS;
    float x = 0.f;
    #pragma unroll
    for (int k = 0; k < NBLOCKS / 256; k++) x += p[t + k * 256];
    // wave reduce (4 waves) then LDS
    #pragma unroll
    for (int o = 32; o > 0; o >>= 1) x += __shfl_down(x, o, 64);
    __shared__ float red[4];
    if ((t & 63) == 0) red[t >> 6] = x;
    __syncthreads();
    if (t == 0) vals[v] = (red[0] + red[1]) + (red[2] + red[3]);
}

// Stage 3: one tiny block reads the 65 value sums in parallel, emits loss.
__global__ __launch_bounds__(128) void heatloss_combine(
        const float* __restrict__ vals_in, float* __restrict__ out) {
    __shared__ float vals[NVALS];
    const int t = threadIdx.x;
    if (t < NVALS) vals[t] = vals_in[t];
    __syncthreads();
    if (t == 0) {
        const float Nf = (float)SPATIAL;  // per-feature element count (B*H*W)
        const float call = vals[64];
        float lf = 0.f, lbg = 0.f, lall = 0.f;
        #pragma unroll
        for (int f = 0; f < F; f++) {
            const float sf = vals[f], cf = vals[16 + f];
            const float dt = vals[32 + f], sa = vals[48 + f];
            lf += (cf > 0.f) ? sf / cf : 0.f;
            const float sbg = dt - sf, cbg = Nf - cf;
            lbg += (cbg > 0.f) ? sbg / cbg : 0.f;
            lall += (call > 0.f) ? sa / call : 0.f;
        }
        out[0] = (lf / 16.f + lbg / 16.f + lall / 16.f) / 3.f;
    }
}

extern "C" void kernel_launch(void* const* d_in, const int* in_sizes, int n_in,
                              void* d_out, int out_size, void* d_ws, size_t ws_size,
                              hipStream_t stream) {
    const float4*       inp = (const float4*)d_in[0];
    const float4*       tgt = (const float4*)d_in[1];
    const unsigned int* msk = (const unsigned int*)d_in[2];   // jnp.bool_ -> 1 byte each
    float* out      = (float*)d_out;
    float* partials = (float*)d_ws;                  // [65][2048] = 532 KB
    float* vals     = partials + NVALS * NBLOCKS;    // [65]

    heatloss_main<<<NBLOCKS, NTHREADS, 0, stream>>>(inp, tgt, msk, partials);
    heatloss_reduce<<<NVALS, 256, 0, stream>>>(partials, vals);
    heatloss_combine<<<1, 128, 0, stream>>>(vals, out);
}